// Round 1
// baseline (1944.080 us; speedup 1.0000x reference)
//
#include <hip/hip_runtime.h>

#define N_NODES 50000
#define N_EDGES 1600000

typedef _Float16 h8 __attribute__((ext_vector_type(8)));
typedef float f4 __attribute__((ext_vector_type(4)));

__device__ inline h8 ld_h8(const _Float16* p) { return *(const h8*)p; }

__device__ inline h8 cvt2h8(f4 a, f4 b) {
    h8 r;
    r[0] = (_Float16)a[0]; r[1] = (_Float16)a[1]; r[2] = (_Float16)a[2]; r[3] = (_Float16)a[3];
    r[4] = (_Float16)b[0]; r[5] = (_Float16)b[1]; r[6] = (_Float16)b[2]; r[7] = (_Float16)b[3];
    return r;
}

// ---------------- prep kernels ----------------

// Transpose + fp16-convert all weight matrices into ws.
// Wm1 (96x128)->Wm1t[128][104]; Wa1 (192x128)->Wa1t[128][200];
// Wm2 (160x128)->Wm2t[128][168]; Wa2 (256x128)->Wa2t[128][256] (unpadded);
// W1 (256x128)->W1t[128][256] (unpadded).
__global__ void prep_weights(const float* __restrict__ Wm1, const float* __restrict__ Wa1,
                             const float* __restrict__ Wm2, const float* __restrict__ Wa2,
                             const float* __restrict__ W1,
                             _Float16* __restrict__ Wm1t, _Float16* __restrict__ Wa1t,
                             _Float16* __restrict__ Wm2t, _Float16* __restrict__ Wa2t,
                             _Float16* __restrict__ W1t)
{
    int i = blockIdx.x * 256 + threadIdx.x;
    if (i < 12288) {                       // 128*96
        int o = i / 96, k = i % 96;
        Wm1t[o * 104 + k] = (_Float16)Wm1[k * 128 + o];
    } else if (i < 36864) {                // + 128*192
        int j = i - 12288; int o = j / 192, k = j % 192;
        Wa1t[o * 200 + k] = (_Float16)Wa1[k * 128 + o];
    } else if (i < 57344) {                // + 128*160
        int j = i - 36864; int o = j / 160, k = j % 160;
        Wm2t[o * 168 + k] = (_Float16)Wm2[k * 128 + o];
    } else if (i < 90112) {                // + 128*256
        int j = i - 57344; int o = j >> 8, k = j & 255;
        Wa2t[(o << 8) + k] = (_Float16)Wa2[k * 128 + o];
    } else if (i < 122880) {               // + 128*256
        int j = i - 90112; int o = j >> 8, k = j & 255;
        W1t[(o << 8) + k] = (_Float16)W1[k * 128 + o];
    }
}

__global__ void cvt_nfeats(const float* __restrict__ nf, _Float16* __restrict__ nf16)
{
    int i = blockIdx.x * 256 + threadIdx.x;   // exactly N*64 = 3.2M threads
    nf16[i] = (_Float16)nf[i];
}

__global__ void count_kernel(const int* __restrict__ dst, float* __restrict__ cntf)
{
    int i = blockIdx.x * 256 + threadIdx.x;   // exactly E threads
    atomicAdd(cntf + dst[i], 1.0f);
}

// ---------------- edge message kernel (fused GEMM + relu + scatter-add) ----------------
// A row (per edge) = [ ntab[src[e]] (KSRC_H fp16) || efeats[e] (32 fp32 -> fp16) ], K = KSRC_H+32
// B = Wt [128][KPAD] fp16 (transposed [out][in]), staged in LDS.
// C[e][128] = relu(A@B + bias), atomicAdd into sacc[dst[e]][128] (skip zeros).
template<int KSRC_H, int KPAD>
__launch_bounds__(256)
__global__ void msg_kernel(const _Float16* __restrict__ ntab,
                           const float* __restrict__ efeats,
                           const int* __restrict__ src,
                           const int* __restrict__ dst,
                           const _Float16* __restrict__ Wt,
                           const float* __restrict__ bias,
                           float* __restrict__ sacc)
{
    constexpr int KSTEPS = (KSRC_H + 32) / 32;
    constexpr int EFSTEP = KSRC_H / 32;
    __shared__ __align__(16) _Float16 Bsh[128 * KPAD];

    const int tid = threadIdx.x;
    {
        const uint4* s4 = (const uint4*)Wt;
        uint4* d4 = (uint4*)Bsh;
        constexpr int n4 = 128 * KPAD / 8;
        for (int i = tid; i < n4; i += 256) d4[i] = s4[i];
    }
    __syncthreads();

    const int wave = tid >> 6, lane = tid & 63;
    const int q = lane >> 4, l15 = lane & 15;
    const int ebase = blockIdx.x * 128 + wave * 32;

    const int eA0 = ebase + l15;
    const int eA1 = ebase + 16 + l15;
    const int s0 = src[eA0], s1 = src[eA1];
    const _Float16* r0 = ntab + (size_t)s0 * KSRC_H;
    const _Float16* r1 = ntab + (size_t)s1 * KSRC_H;

    f4 acc[2][8];
#pragma unroll
    for (int t = 0; t < 2; t++)
#pragma unroll
        for (int nt = 0; nt < 8; nt++) acc[t][nt] = (f4){0.f, 0.f, 0.f, 0.f};

#pragma unroll
    for (int ks = 0; ks < KSTEPS; ks++) {
        h8 a0, a1;
        if (ks < EFSTEP) {
            a0 = ld_h8(r0 + ks * 32 + q * 8);
            a1 = ld_h8(r1 + ks * 32 + q * 8);
        } else {
            const float* e0 = efeats + (size_t)eA0 * 32 + q * 8;
            const float* e1 = efeats + (size_t)eA1 * 32 + q * 8;
            a0 = cvt2h8(*(const f4*)e0, *(const f4*)(e0 + 4));
            a1 = cvt2h8(*(const f4*)e1, *(const f4*)(e1 + 4));
        }
#pragma unroll
        for (int nt = 0; nt < 8; nt++) {
            h8 b = ld_h8(&Bsh[(nt * 16 + l15) * KPAD + ks * 32 + q * 8]);
            acc[0][nt] = __builtin_amdgcn_mfma_f32_16x16x32_f16(a0, b, acc[0][nt], 0, 0, 0);
            acc[1][nt] = __builtin_amdgcn_mfma_f32_16x16x32_f16(a1, b, acc[1][nt], 0, 0, 0);
        }
    }

    int dsts[2][4];
#pragma unroll
    for (int t = 0; t < 2; t++)
#pragma unroll
        for (int r = 0; r < 4; r++)
            dsts[t][r] = dst[ebase + t * 16 + q * 4 + r];

#pragma unroll
    for (int nt = 0; nt < 8; nt++) {
        const int col = nt * 16 + l15;
        const float bv = bias[col];
#pragma unroll
        for (int t = 0; t < 2; t++)
#pragma unroll
            for (int r = 0; r < 4; r++) {
                float v = acc[t][nt][r] + bv;
                if (v > 0.f) atomicAdd(sacc + (size_t)dsts[t][r] * 128 + col, v);
            }
    }
}

// ---------------- node apply kernel ----------------
// A row (per node) = [ ntab[n] (KSRC_H fp16) || (sacc[n]/max(cnt,1)) (128 fp32 -> fp16) ]
// out = relu(A@B + bias) stored fp16.
template<int KSRC_H, bool SWIZ, int KPAD>
__launch_bounds__(256)
__global__ void apply_kernel(const _Float16* __restrict__ ntab,
                             const float* __restrict__ sacc,
                             const float* __restrict__ cntf,
                             const _Float16* __restrict__ Wt,
                             const float* __restrict__ bias,
                             _Float16* __restrict__ outtab)
{
    constexpr int KSTEPS = (KSRC_H + 128) / 32;
    __shared__ __align__(16) _Float16 Bsh[128 * KPAD];

    const int tid = threadIdx.x;
    if (SWIZ) {
        const uint4* s4 = (const uint4*)Wt;
        uint4* d4 = (uint4*)Bsh;
        for (int i = tid; i < 4096; i += 256) {
            int n = i >> 5, c = i & 31;
            d4[(n << 5) | (c ^ (n & 31))] = s4[i];
        }
    } else {
        const uint4* s4 = (const uint4*)Wt;
        uint4* d4 = (uint4*)Bsh;
        constexpr int n4 = 128 * KPAD / 8;
        for (int i = tid; i < n4; i += 256) d4[i] = s4[i];
    }
    __syncthreads();

    const int wave = tid >> 6, lane = tid & 63;
    const int q = lane >> 4, l15 = lane & 15;
    const int nbase = blockIdx.x * 128 + wave * 32;

    const int n0 = nbase + l15, n1 = nbase + 16 + l15;
    const int n0c = min(n0, N_NODES - 1), n1c = min(n1, N_NODES - 1);
    const _Float16* r0 = ntab + (size_t)n0c * KSRC_H;
    const _Float16* r1 = ntab + (size_t)n1c * KSRC_H;
    const float rcp0 = 1.0f / fmaxf(cntf[n0c], 1.0f);
    const float rcp1 = 1.0f / fmaxf(cntf[n1c], 1.0f);

    f4 acc[2][8];
#pragma unroll
    for (int t = 0; t < 2; t++)
#pragma unroll
        for (int nt = 0; nt < 8; nt++) acc[t][nt] = (f4){0.f, 0.f, 0.f, 0.f};

#pragma unroll
    for (int ks = 0; ks < KSTEPS; ks++) {
        h8 a0, a1;
        if (ks < KSRC_H / 32) {
            a0 = ld_h8(r0 + ks * 32 + q * 8);
            a1 = ld_h8(r1 + ks * 32 + q * 8);
        } else {
            const int kk = ks * 32 - KSRC_H + q * 8;
            const float* p0 = sacc + (size_t)n0c * 128 + kk;
            const float* p1 = sacc + (size_t)n1c * 128 + kk;
            f4 u0 = *(const f4*)p0 * rcp0, v0 = *(const f4*)(p0 + 4) * rcp0;
            f4 u1 = *(const f4*)p1 * rcp1, v1 = *(const f4*)(p1 + 4) * rcp1;
            a0 = cvt2h8(u0, v0);
            a1 = cvt2h8(u1, v1);
        }
#pragma unroll
        for (int nt = 0; nt < 8; nt++) {
            h8 b;
            if (SWIZ) {
                const int nrow = nt * 16 + l15;
                const int chunk = ((ks << 2) | q) ^ (nrow & 31);
                b = ld_h8(Bsh + (((nrow << 5) | chunk) << 3));
            } else {
                b = ld_h8(&Bsh[(nt * 16 + l15) * KPAD + ks * 32 + q * 8]);
            }
            acc[0][nt] = __builtin_amdgcn_mfma_f32_16x16x32_f16(a0, b, acc[0][nt], 0, 0, 0);
            acc[1][nt] = __builtin_amdgcn_mfma_f32_16x16x32_f16(a1, b, acc[1][nt], 0, 0, 0);
        }
    }

#pragma unroll
    for (int nt = 0; nt < 8; nt++) {
        const int col = nt * 16 + l15;
        const float bv = bias[col];
#pragma unroll
        for (int t = 0; t < 2; t++)
#pragma unroll
            for (int r = 0; r < 4; r++) {
                const int node = nbase + t * 16 + q * 4 + r;
                if (node < N_NODES) {
                    float v = fmaxf(acc[t][nt][r] + bv, 0.f);
                    outtab[(size_t)node * 128 + col] = (_Float16)v;
                }
            }
    }
}

// ---------------- edge predictor kernel ----------------
// z = [h2[src[e]] || h2[dst[e]]] (256 fp16); y = relu(z@W1+b1); out = y@W2 + b2 (fp32).
__launch_bounds__(256)
__global__ void pred_kernel(const _Float16* __restrict__ h2,
                            const int* __restrict__ src,
                            const int* __restrict__ dst,
                            const _Float16* __restrict__ W1t,  // [128][256] unpadded
                            const float* __restrict__ b1,
                            const float* __restrict__ W2,      // [128][2] fp32
                            const float* __restrict__ b2,
                            float* __restrict__ out)
{
    __shared__ __align__(16) _Float16 Bsh[128 * 256];

    const int tid = threadIdx.x;
    {
        const uint4* s4 = (const uint4*)W1t;
        uint4* d4 = (uint4*)Bsh;
        for (int i = tid; i < 4096; i += 256) {
            int n = i >> 5, c = i & 31;
            d4[(n << 5) | (c ^ (n & 31))] = s4[i];
        }
    }
    __syncthreads();

    const int wave = tid >> 6, lane = tid & 63;
    const int q = lane >> 4, l15 = lane & 15;
    const int ebase = blockIdx.x * 128 + wave * 32;

    const int e0 = ebase + l15, e1 = ebase + 16 + l15;
    const _Float16* rs0 = h2 + (size_t)src[e0] * 128;
    const _Float16* rd0 = h2 + (size_t)dst[e0] * 128;
    const _Float16* rs1 = h2 + (size_t)src[e1] * 128;
    const _Float16* rd1 = h2 + (size_t)dst[e1] * 128;

    f4 acc[2][8];
#pragma unroll
    for (int t = 0; t < 2; t++)
#pragma unroll
        for (int nt = 0; nt < 8; nt++) acc[t][nt] = (f4){0.f, 0.f, 0.f, 0.f};

#pragma unroll
    for (int ks = 0; ks < 8; ks++) {
        h8 a0, a1;
        if (ks < 4) {
            a0 = ld_h8(rs0 + ks * 32 + q * 8);
            a1 = ld_h8(rs1 + ks * 32 + q * 8);
        } else {
            a0 = ld_h8(rd0 + (ks - 4) * 32 + q * 8);
            a1 = ld_h8(rd1 + (ks - 4) * 32 + q * 8);
        }
#pragma unroll
        for (int nt = 0; nt < 8; nt++) {
            const int nrow = nt * 16 + l15;
            const int chunk = ((ks << 2) | q) ^ (nrow & 31);
            h8 b = ld_h8(Bsh + (((nrow << 5) | chunk) << 3));
            acc[0][nt] = __builtin_amdgcn_mfma_f32_16x16x32_f16(a0, b, acc[0][nt], 0, 0, 0);
            acc[1][nt] = __builtin_amdgcn_mfma_f32_16x16x32_f16(a1, b, acc[1][nt], 0, 0, 0);
        }
    }

    // y = relu(acc + b1), then o[t][r][c] = sum_n y[t][n][r] * W2[n][c]
    float o[2][4][2];
#pragma unroll
    for (int t = 0; t < 2; t++)
#pragma unroll
        for (int r = 0; r < 4; r++) { o[t][r][0] = 0.f; o[t][r][1] = 0.f; }

#pragma unroll
    for (int nt = 0; nt < 8; nt++) {
        const int nrow = nt * 16 + l15;
        const float bv = b1[nrow];
        const float w20 = W2[nrow * 2 + 0];
        const float w21 = W2[nrow * 2 + 1];
#pragma unroll
        for (int t = 0; t < 2; t++)
#pragma unroll
            for (int r = 0; r < 4; r++) {
                float y = fmaxf(acc[t][nt][r] + bv, 0.f);
                o[t][r][0] += y * w20;
                o[t][r][1] += y * w21;
            }
    }

    // reduce across the 16 lanes of each quad
#pragma unroll
    for (int m = 1; m < 16; m <<= 1) {
#pragma unroll
        for (int t = 0; t < 2; t++)
#pragma unroll
            for (int r = 0; r < 4; r++) {
                o[t][r][0] += __shfl_xor(o[t][r][0], m, 64);
                o[t][r][1] += __shfl_xor(o[t][r][1], m, 64);
            }
    }

    if (l15 < 8) {
        const int r = l15 >> 1, c = l15 & 1;
        const float bb = c ? b2[1] : b2[0];
#pragma unroll
        for (int t = 0; t < 2; t++) {
            float v0 = (r == 0) ? o[t][0][0] : (r == 1) ? o[t][1][0] : (r == 2) ? o[t][2][0] : o[t][3][0];
            float v1 = (r == 0) ? o[t][0][1] : (r == 1) ? o[t][1][1] : (r == 2) ? o[t][2][1] : o[t][3][1];
            float v = (c ? v1 : v0) + bb;
            out[(size_t)(ebase + t * 16 + q * 4 + r) * 2 + c] = v;
        }
    }
}

// ---------------- launch ----------------

extern "C" void kernel_launch(void* const* d_in, const int* in_sizes, int n_in,
                              void* d_out, int out_size, void* d_ws, size_t ws_size,
                              hipStream_t stream)
{
    const float* nfeats = (const float*)d_in[0];
    const float* efeats = (const float*)d_in[1];
    const int*   src    = (const int*)d_in[2];
    const int*   dst    = (const int*)d_in[3];
    const float* Wm1 = (const float*)d_in[4],  *bm1 = (const float*)d_in[5];
    const float* Wa1 = (const float*)d_in[6],  *ba1 = (const float*)d_in[7];
    const float* Wm2 = (const float*)d_in[8],  *bm2 = (const float*)d_in[9];
    const float* Wa2 = (const float*)d_in[10], *ba2 = (const float*)d_in[11];
    const float* W1  = (const float*)d_in[12], *b1  = (const float*)d_in[13];
    const float* W2  = (const float*)d_in[14], *b2  = (const float*)d_in[15];
    float* out = (float*)d_out;

    char* ws = (char*)d_ws;
    float*     s    = (float*)(ws);                   // N*128*4 = 25,600,000 B
    float*     cntf = (float*)(ws + 25600000);        // N*4     =    200,000 B
    _Float16*  nf16 = (_Float16*)(ws + 25800000);     // N*64*2  =  6,400,000 B
    _Float16*  h1   = (_Float16*)(ws + 32200000);     // N*128*2 = 12,800,000 B
    _Float16*  h2   = (_Float16*)(ws + 45000000);     // N*128*2 = 12,800,000 B
    _Float16*  Wm1t = (_Float16*)(ws + 57800000);     // 128*104*2 = 26,624 B
    _Float16*  Wa1t = (_Float16*)(ws + 57826624);     // 128*200*2 = 51,200 B
    _Float16*  Wm2t = (_Float16*)(ws + 57877824);     // 128*168*2 = 43,008 B
    _Float16*  Wa2t = (_Float16*)(ws + 57920832);     // 128*256*2 = 65,536 B
    _Float16*  W1t  = (_Float16*)(ws + 57986368);     // 128*256*2 = 65,536 B

    hipMemsetAsync(s, 0, 25600000, stream);
    hipMemsetAsync(cntf, 0, 200000, stream);

    prep_weights<<<480, 256, 0, stream>>>(Wm1, Wa1, Wm2, Wa2, W1, Wm1t, Wa1t, Wm2t, Wa2t, W1t);
    cvt_nfeats<<<12500, 256, 0, stream>>>(nfeats, nf16);
    count_kernel<<<6250, 256, 0, stream>>>(dst, cntf);

    // layer 1
    msg_kernel<64, 104><<<12500, 256, 0, stream>>>(nf16, efeats, src, dst, Wm1t, bm1, s);
    apply_kernel<64, false, 200><<<391, 256, 0, stream>>>(nf16, s, cntf, Wa1t, ba1, h1);

    // layer 2 (reuse s)
    hipMemsetAsync(s, 0, 25600000, stream);
    msg_kernel<128, 168><<<12500, 256, 0, stream>>>(h1, efeats, src, dst, Wm2t, bm2, s);
    apply_kernel<128, true, 256><<<391, 256, 0, stream>>>(h1, s, cntf, Wa2t, ba2, h2);

    // predictor
    pred_kernel<<<12500, 256, 0, stream>>>(h2, src, dst, W1t, b1, W2, b2, out);
}

// Round 2
// 1393.590 us; speedup vs baseline: 1.3950x; 1.3950x over previous
//
#include <hip/hip_runtime.h>

#define N_NODES 50000
#define N_EDGES 1600000

typedef _Float16 h8 __attribute__((ext_vector_type(8)));
typedef float f4 __attribute__((ext_vector_type(4)));

__device__ inline h8 ld_h8(const _Float16* p) { return *(const h8*)p; }

__device__ inline h8 cvt2h8(f4 a, f4 b) {
    h8 r;
    r[0] = (_Float16)a[0]; r[1] = (_Float16)a[1]; r[2] = (_Float16)a[2]; r[3] = (_Float16)a[3];
    r[4] = (_Float16)b[0]; r[5] = (_Float16)b[1]; r[6] = (_Float16)b[2]; r[7] = (_Float16)b[3];
    return r;
}

// ---------------- prep kernels ----------------

__global__ void prep_weights(const float* __restrict__ Wm1, const float* __restrict__ Wa1,
                             const float* __restrict__ Wm2, const float* __restrict__ Wa2,
                             const float* __restrict__ W1,
                             _Float16* __restrict__ Wm1t, _Float16* __restrict__ Wa1t,
                             _Float16* __restrict__ Wm2t, _Float16* __restrict__ Wa2t,
                             _Float16* __restrict__ W1t)
{
    int i = blockIdx.x * 256 + threadIdx.x;
    if (i < 12288) {                       // 128*96
        int o = i / 96, k = i % 96;
        Wm1t[o * 104 + k] = (_Float16)Wm1[k * 128 + o];
    } else if (i < 36864) {                // + 128*192
        int j = i - 12288; int o = j / 192, k = j % 192;
        Wa1t[o * 200 + k] = (_Float16)Wa1[k * 128 + o];
    } else if (i < 57344) {                // + 128*160
        int j = i - 36864; int o = j / 160, k = j % 160;
        Wm2t[o * 168 + k] = (_Float16)Wm2[k * 128 + o];
    } else if (i < 90112) {                // + 128*256
        int j = i - 57344; int o = j >> 8, k = j & 255;
        Wa2t[(o << 8) + k] = (_Float16)Wa2[k * 128 + o];
    } else if (i < 122880) {               // + 128*256
        int j = i - 90112; int o = j >> 8, k = j & 255;
        W1t[(o << 8) + k] = (_Float16)W1[k * 128 + o];
    }
}

__global__ void cvt_nfeats(const float* __restrict__ nf, _Float16* __restrict__ nf16)
{
    int i = blockIdx.x * 256 + threadIdx.x;   // exactly N*64 = 3.2M threads
    nf16[i] = (_Float16)nf[i];
}

// ---------------- counting sort of edges by dst ----------------

__global__ void hist_kernel(const int* __restrict__ dst, int* __restrict__ cnt)
{
    int e = blockIdx.x * 256 + threadIdx.x;   // exactly E threads
    atomicAdd(cnt + dst[e], 1);
}

__global__ void scan1_kernel(const int* __restrict__ cnt, int* __restrict__ tmp,
                             int* __restrict__ bsum)
{
    __shared__ int sh[256];
    int t = threadIdx.x, i = blockIdx.x * 256 + t;
    int v = (i < N_NODES) ? cnt[i] : 0;
    sh[t] = v; __syncthreads();
    for (int off = 1; off < 256; off <<= 1) {
        int x = (t >= off) ? sh[t - off] : 0;
        __syncthreads();
        sh[t] += x;
        __syncthreads();
    }
    if (i < N_NODES) tmp[i] = sh[t];
    if (t == 255) bsum[blockIdx.x] = sh[255];
}

__global__ void scan2_kernel(const int* __restrict__ bsum, int* __restrict__ bbase)
{
    __shared__ int sh[256];
    int t = threadIdx.x;
    int v = (t < 196) ? bsum[t] : 0;
    sh[t] = v; __syncthreads();
    for (int off = 1; off < 256; off <<= 1) {
        int x = (t >= off) ? sh[t - off] : 0;
        __syncthreads();
        sh[t] += x;
        __syncthreads();
    }
    if (t < 196) bbase[t] = sh[t] - v;   // exclusive
}

__global__ void scan3_kernel(const int* __restrict__ cnt, const int* __restrict__ tmp,
                             const int* __restrict__ bbase, int* __restrict__ cursor)
{
    int t = threadIdx.x, b = blockIdx.x, i = b * 256 + t;
    if (i < N_NODES) cursor[i] = tmp[i] - cnt[i] + bbase[b];
}

__global__ void scatter_kernel(const int* __restrict__ dst, int* __restrict__ cursor,
                               int* __restrict__ perm)
{
    int e = blockIdx.x * 256 + threadIdx.x;   // exactly E threads
    int d = dst[e];
    int pos = atomicAdd(cursor + d, 1);
    perm[pos] = e;
}

// ---------------- edge message kernel (GEMM + relu + segmented reduce + few atomics) ----
// Block handles 128 dst-sorted edge slots. A row (per edge) =
// [ ntab[src[perm[slot]]] (KSRC_H fp16) || efeats[perm[slot]] (32 fp32 -> fp16) ].
// B = Wt [128][KPAD] fp16 in LDS. After GEMM the 128x128 relu'd tile goes to LDS
// (two 64-row passes, aliasing the B buffer) and a segmented sum over the sorted
// dst emits ~8 atomics/col/block instead of 128.
template<int KSRC_H, int KPAD>
__launch_bounds__(256)
__global__ void msg_kernel_sorted(const _Float16* __restrict__ ntab,
                                  const float* __restrict__ efeats,
                                  const int* __restrict__ perm,
                                  const int* __restrict__ src,
                                  const int* __restrict__ dst,
                                  const _Float16* __restrict__ Wt,
                                  const float* __restrict__ bias,
                                  float* __restrict__ sacc)
{
    constexpr int KSTEPS = (KSRC_H + 32) / 32;
    constexpr int EFSTEP = KSRC_H / 32;
    constexpr int BBYTES = 128 * KPAD * 2;
    constexpr int TBYTES = 64 * 132 * 4;            // 64-row fp32 tile, pad 132
    constexpr int SBYTES = BBYTES > TBYTES ? BBYTES : TBYTES;
    __shared__ __align__(16) char smem[SBYTES];
    __shared__ int dsh[128];
    _Float16* Bsh = (_Float16*)smem;
    float* tile = (float*)smem;

    const int tid = threadIdx.x;
    {
        const uint4* s4 = (const uint4*)Wt;
        uint4* d4 = (uint4*)smem;
        constexpr int n4 = BBYTES / 16;
        for (int i = tid; i < n4; i += 256) d4[i] = s4[i];
    }
    if (tid < 128) {
        int e = perm[blockIdx.x * 128 + tid];
        dsh[tid] = dst[e];
    }
    __syncthreads();

    const int wave = tid >> 6, lane = tid & 63;
    const int q = lane >> 4, l15 = lane & 15;
    const int ebase = blockIdx.x * 128 + wave * 32;

    const int slot0 = ebase + l15, slot1 = ebase + 16 + l15;
    const int e0 = perm[slot0], e1 = perm[slot1];
    const int s0 = src[e0], s1 = src[e1];
    const _Float16* r0 = ntab + (size_t)s0 * KSRC_H;
    const _Float16* r1 = ntab + (size_t)s1 * KSRC_H;

    f4 acc[2][8];
#pragma unroll
    for (int t = 0; t < 2; t++)
#pragma unroll
        for (int nt = 0; nt < 8; nt++) acc[t][nt] = (f4){0.f, 0.f, 0.f, 0.f};

#pragma unroll
    for (int ks = 0; ks < KSTEPS; ks++) {
        h8 a0, a1;
        if (ks < EFSTEP) {
            a0 = ld_h8(r0 + ks * 32 + q * 8);
            a1 = ld_h8(r1 + ks * 32 + q * 8);
        } else {
            const float* p0 = efeats + (size_t)e0 * 32 + q * 8;
            const float* p1 = efeats + (size_t)e1 * 32 + q * 8;
            a0 = cvt2h8(*(const f4*)p0, *(const f4*)(p0 + 4));
            a1 = cvt2h8(*(const f4*)p1, *(const f4*)(p1 + 4));
        }
#pragma unroll
        for (int nt = 0; nt < 8; nt++) {
            h8 b = ld_h8(&Bsh[(nt * 16 + l15) * KPAD + ks * 32 + q * 8]);
            acc[0][nt] = __builtin_amdgcn_mfma_f32_16x16x32_f16(a0, b, acc[0][nt], 0, 0, 0);
            acc[1][nt] = __builtin_amdgcn_mfma_f32_16x16x32_f16(a1, b, acc[1][nt], 0, 0, 0);
        }
    }

    __syncthreads();   // all waves done reading Bsh; tile aliases it

    // two passes: pass p covers global rows [64p, 64p+64) = waves 2p, 2p+1
#pragma unroll
    for (int p = 0; p < 2; p++) {
        if ((wave >> 1) == p) {
            const int wrow = (wave & 1) * 32;     // row base within 64-row tile
#pragma unroll
            for (int nt = 0; nt < 8; nt++) {
                const int col = nt * 16 + l15;
                const float bv = bias[col];
#pragma unroll
                for (int t = 0; t < 2; t++)
#pragma unroll
                    for (int r = 0; r < 4; r++) {
                        const int row = wrow + t * 16 + q * 4 + r;
                        tile[row * 132 + col] = fmaxf(acc[t][nt][r] + bv, 0.f);
                    }
            }
        }
        __syncthreads();
        {
            const int col = tid & 127;
            const int h = tid >> 7;               // half of the 64-row tile
            const int dbase = p * 64 + h * 32;    // index into dsh
            float a = 0.f;
            int dprev = dsh[dbase];
#pragma unroll 4
            for (int rr = 0; rr < 32; rr++) {
                int d = dsh[dbase + rr];
                float v = tile[(h * 32 + rr) * 132 + col];
                if (d != dprev) {
                    atomicAdd(sacc + (size_t)dprev * 128 + col, a);
                    a = v; dprev = d;
                } else {
                    a += v;
                }
            }
            atomicAdd(sacc + (size_t)dprev * 128 + col, a);
        }
        __syncthreads();
    }
}

// ---------------- node apply kernel ----------------
template<int KSRC_H, bool SWIZ, int KPAD>
__launch_bounds__(256)
__global__ void apply_kernel(const _Float16* __restrict__ ntab,
                             const float* __restrict__ sacc,
                             const int* __restrict__ cnt,
                             const _Float16* __restrict__ Wt,
                             const float* __restrict__ bias,
                             _Float16* __restrict__ outtab)
{
    constexpr int KSTEPS = (KSRC_H + 128) / 32;
    __shared__ __align__(16) _Float16 Bsh[128 * KPAD];

    const int tid = threadIdx.x;
    if (SWIZ) {
        const uint4* s4 = (const uint4*)Wt;
        uint4* d4 = (uint4*)Bsh;
        for (int i = tid; i < 4096; i += 256) {
            int n = i >> 5, c = i & 31;
            d4[(n << 5) | (c ^ (n & 31))] = s4[i];
        }
    } else {
        const uint4* s4 = (const uint4*)Wt;
        uint4* d4 = (uint4*)Bsh;
        constexpr int n4 = 128 * KPAD / 8;
        for (int i = tid; i < n4; i += 256) d4[i] = s4[i];
    }
    __syncthreads();

    const int wave = tid >> 6, lane = tid & 63;
    const int q = lane >> 4, l15 = lane & 15;
    const int nbase = blockIdx.x * 128 + wave * 32;

    const int n0 = nbase + l15, n1 = nbase + 16 + l15;
    const int n0c = min(n0, N_NODES - 1), n1c = min(n1, N_NODES - 1);
    const _Float16* r0 = ntab + (size_t)n0c * KSRC_H;
    const _Float16* r1 = ntab + (size_t)n1c * KSRC_H;
    const float rcp0 = 1.0f / fmaxf((float)cnt[n0c], 1.0f);
    const float rcp1 = 1.0f / fmaxf((float)cnt[n1c], 1.0f);

    f4 acc[2][8];
#pragma unroll
    for (int t = 0; t < 2; t++)
#pragma unroll
        for (int nt = 0; nt < 8; nt++) acc[t][nt] = (f4){0.f, 0.f, 0.f, 0.f};

#pragma unroll
    for (int ks = 0; ks < KSTEPS; ks++) {
        h8 a0, a1;
        if (ks < KSRC_H / 32) {
            a0 = ld_h8(r0 + ks * 32 + q * 8);
            a1 = ld_h8(r1 + ks * 32 + q * 8);
        } else {
            const int kk = ks * 32 - KSRC_H + q * 8;
            const float* p0 = sacc + (size_t)n0c * 128 + kk;
            const float* p1 = sacc + (size_t)n1c * 128 + kk;
            f4 u0 = *(const f4*)p0 * rcp0, v0 = *(const f4*)(p0 + 4) * rcp0;
            f4 u1 = *(const f4*)p1 * rcp1, v1 = *(const f4*)(p1 + 4) * rcp1;
            a0 = cvt2h8(u0, v0);
            a1 = cvt2h8(u1, v1);
        }
#pragma unroll
        for (int nt = 0; nt < 8; nt++) {
            h8 b;
            if (SWIZ) {
                const int nrow = nt * 16 + l15;
                const int chunk = ((ks << 2) | q) ^ (nrow & 31);
                b = ld_h8(Bsh + (((nrow << 5) | chunk) << 3));
            } else {
                b = ld_h8(&Bsh[(nt * 16 + l15) * KPAD + ks * 32 + q * 8]);
            }
            acc[0][nt] = __builtin_amdgcn_mfma_f32_16x16x32_f16(a0, b, acc[0][nt], 0, 0, 0);
            acc[1][nt] = __builtin_amdgcn_mfma_f32_16x16x32_f16(a1, b, acc[1][nt], 0, 0, 0);
        }
    }

#pragma unroll
    for (int nt = 0; nt < 8; nt++) {
        const int col = nt * 16 + l15;
        const float bv = bias[col];
#pragma unroll
        for (int t = 0; t < 2; t++)
#pragma unroll
            for (int r = 0; r < 4; r++) {
                const int node = nbase + t * 16 + q * 4 + r;
                if (node < N_NODES) {
                    float v = fmaxf(acc[t][nt][r] + bv, 0.f);
                    outtab[(size_t)node * 128 + col] = (_Float16)v;
                }
            }
    }
}

// ---------------- edge predictor kernel ----------------
__launch_bounds__(256)
__global__ void pred_kernel(const _Float16* __restrict__ h2,
                            const int* __restrict__ src,
                            const int* __restrict__ dst,
                            const _Float16* __restrict__ W1t,  // [128][256] unpadded
                            const float* __restrict__ b1,
                            const float* __restrict__ W2,      // [128][2] fp32
                            const float* __restrict__ b2,
                            float* __restrict__ out)
{
    __shared__ __align__(16) _Float16 Bsh[128 * 256];

    const int tid = threadIdx.x;
    {
        const uint4* s4 = (const uint4*)W1t;
        uint4* d4 = (uint4*)Bsh;
        for (int i = tid; i < 4096; i += 256) {
            int n = i >> 5, c = i & 31;
            d4[(n << 5) | (c ^ (n & 31))] = s4[i];
        }
    }
    __syncthreads();

    const int wave = tid >> 6, lane = tid & 63;
    const int q = lane >> 4, l15 = lane & 15;
    const int ebase = blockIdx.x * 128 + wave * 32;

    const int e0 = ebase + l15, e1 = ebase + 16 + l15;
    const _Float16* rs0 = h2 + (size_t)src[e0] * 128;
    const _Float16* rd0 = h2 + (size_t)dst[e0] * 128;
    const _Float16* rs1 = h2 + (size_t)src[e1] * 128;
    const _Float16* rd1 = h2 + (size_t)dst[e1] * 128;

    f4 acc[2][8];
#pragma unroll
    for (int t = 0; t < 2; t++)
#pragma unroll
        for (int nt = 0; nt < 8; nt++) acc[t][nt] = (f4){0.f, 0.f, 0.f, 0.f};

#pragma unroll
    for (int ks = 0; ks < 8; ks++) {
        h8 a0, a1;
        if (ks < 4) {
            a0 = ld_h8(rs0 + ks * 32 + q * 8);
            a1 = ld_h8(rs1 + ks * 32 + q * 8);
        } else {
            a0 = ld_h8(rd0 + (ks - 4) * 32 + q * 8);
            a1 = ld_h8(rd1 + (ks - 4) * 32 + q * 8);
        }
#pragma unroll
        for (int nt = 0; nt < 8; nt++) {
            const int nrow = nt * 16 + l15;
            const int chunk = ((ks << 2) | q) ^ (nrow & 31);
            h8 b = ld_h8(Bsh + (((nrow << 5) | chunk) << 3));
            acc[0][nt] = __builtin_amdgcn_mfma_f32_16x16x32_f16(a0, b, acc[0][nt], 0, 0, 0);
            acc[1][nt] = __builtin_amdgcn_mfma_f32_16x16x32_f16(a1, b, acc[1][nt], 0, 0, 0);
        }
    }

    float o[2][4][2];
#pragma unroll
    for (int t = 0; t < 2; t++)
#pragma unroll
        for (int r = 0; r < 4; r++) { o[t][r][0] = 0.f; o[t][r][1] = 0.f; }

#pragma unroll
    for (int nt = 0; nt < 8; nt++) {
        const int nrow = nt * 16 + l15;
        const float bv = b1[nrow];
        const float w20 = W2[nrow * 2 + 0];
        const float w21 = W2[nrow * 2 + 1];
#pragma unroll
        for (int t = 0; t < 2; t++)
#pragma unroll
            for (int r = 0; r < 4; r++) {
                float y = fmaxf(acc[t][nt][r] + bv, 0.f);
                o[t][r][0] += y * w20;
                o[t][r][1] += y * w21;
            }
    }

#pragma unroll
    for (int m = 1; m < 16; m <<= 1) {
#pragma unroll
        for (int t = 0; t < 2; t++)
#pragma unroll
            for (int r = 0; r < 4; r++) {
                o[t][r][0] += __shfl_xor(o[t][r][0], m, 64);
                o[t][r][1] += __shfl_xor(o[t][r][1], m, 64);
            }
    }

    if (l15 < 8) {
        const int r = l15 >> 1, c = l15 & 1;
        const float bb = c ? b2[1] : b2[0];
#pragma unroll
        for (int t = 0; t < 2; t++) {
            float v0 = (r == 0) ? o[t][0][0] : (r == 1) ? o[t][1][0] : (r == 2) ? o[t][2][0] : o[t][3][0];
            float v1 = (r == 0) ? o[t][0][1] : (r == 1) ? o[t][1][1] : (r == 2) ? o[t][2][1] : o[t][3][1];
            float v = (c ? v1 : v0) + bb;
            out[(size_t)(ebase + t * 16 + q * 4 + r) * 2 + c] = v;
        }
    }
}

// ---------------- launch ----------------

extern "C" void kernel_launch(void* const* d_in, const int* in_sizes, int n_in,
                              void* d_out, int out_size, void* d_ws, size_t ws_size,
                              hipStream_t stream)
{
    const float* nfeats = (const float*)d_in[0];
    const float* efeats = (const float*)d_in[1];
    const int*   src    = (const int*)d_in[2];
    const int*   dst    = (const int*)d_in[3];
    const float* Wm1 = (const float*)d_in[4],  *bm1 = (const float*)d_in[5];
    const float* Wa1 = (const float*)d_in[6],  *ba1 = (const float*)d_in[7];
    const float* Wm2 = (const float*)d_in[8],  *bm2 = (const float*)d_in[9];
    const float* Wa2 = (const float*)d_in[10], *ba2 = (const float*)d_in[11];
    const float* W1  = (const float*)d_in[12], *b1  = (const float*)d_in[13];
    const float* W2  = (const float*)d_in[14], *b2  = (const float*)d_in[15];
    float* out = (float*)d_out;

    char* ws = (char*)d_ws;
    float*     s     = (float*)(ws);                   // 25,600,000 B
    int*       cnt   = (int*)(ws + 25600000);          //    200,000 B
    int*       tmp   = (int*)(ws + 25800000);          //    200,000 B
    int*       cursor= (int*)(ws + 26000000);          //    200,000 B
    int*       bsum  = (int*)(ws + 26200000);          //      1,024 B
    int*       bbase = (int*)(ws + 26201024);          //      1,024 B
    _Float16*  nf16  = (_Float16*)(ws + 26202048);     //  6,400,000 B
    int*       perm  = (int*)(ws + 32602048);          //  6,400,000 B
    _Float16*  h1    = (_Float16*)(ws + 39002048);     // 12,800,000 B
    _Float16*  h2    = (_Float16*)(ws + 26202048);     // 12,800,000 B (aliases nf16+perm, both dead by then)
    _Float16*  Wm1t  = (_Float16*)(ws + 51802048);     //     26,624 B
    _Float16*  Wa1t  = (_Float16*)(ws + 51828672);     //     51,200 B
    _Float16*  Wm2t  = (_Float16*)(ws + 51879872);     //     43,008 B
    _Float16*  Wa2t  = (_Float16*)(ws + 51922880);     //     65,536 B
    _Float16*  W1t   = (_Float16*)(ws + 51988416);     //     65,536 B

    hipMemsetAsync(s, 0, 25600000, stream);
    hipMemsetAsync(cnt, 0, 200000, stream);

    prep_weights<<<480, 256, 0, stream>>>(Wm1, Wa1, Wm2, Wa2, W1, Wm1t, Wa1t, Wm2t, Wa2t, W1t);
    cvt_nfeats<<<12500, 256, 0, stream>>>(nfeats, nf16);

    // counting sort of edges by dst
    hist_kernel<<<6250, 256, 0, stream>>>(dst, cnt);
    scan1_kernel<<<196, 256, 0, stream>>>(cnt, tmp, bsum);
    scan2_kernel<<<1, 256, 0, stream>>>(bsum, bbase);
    scan3_kernel<<<196, 256, 0, stream>>>(cnt, tmp, bbase, cursor);
    scatter_kernel<<<6250, 256, 0, stream>>>(dst, cursor, perm);

    // layer 1
    msg_kernel_sorted<64, 104><<<12500, 256, 0, stream>>>(nf16, efeats, perm, src, dst, Wm1t, bm1, s);
    apply_kernel<64, false, 200><<<391, 256, 0, stream>>>(nf16, s, cnt, Wa1t, ba1, h1);

    // layer 2 (reuse s)
    hipMemsetAsync(s, 0, 25600000, stream);
    msg_kernel_sorted<128, 168><<<12500, 256, 0, stream>>>(h1, efeats, perm, src, dst, Wm2t, bm2, s);
    apply_kernel<128, true, 256><<<391, 256, 0, stream>>>(h1, s, cnt, Wa2t, ba2, h2);

    // predictor
    pred_kernel<<<12500, 256, 0, stream>>>(h2, src, dst, W1t, b1, W2, b2, out);
}